// Round 7
// baseline (84.964 us; speedup 1.0000x reference)
//
#include <hip/hip_runtime.h>

// Chamfer distance via bf16 MFMA with split-bf16 (hi+lo) distance packing.
// B=4, N=M=8192, f32 in/out. out = [dist1 (B*N) | dist2 (B*M)].
//
// d[i][j] = |q_i|^2 + |r_j|^2 - 2 q_i.r_j computed entirely inside
// v_mfma_f32_32x32x16_bf16 via K=16 slot packing (see chamfer_prep).
//
// R6 = R5's proven numerics (nested-fminf min3 fold; NO inline-asm min on
// MFMA outputs; separate out-init) with scheduling fixes:
//   - QPW 2 -> 1: peak VGPR ~100 (was ~150 vs 128 cap) — no serialization
//   - 6-register tile ring: loads issued 2 pair-iters (~200cyc) ahead of use
//   - SEGR=2, 64 q-panels: same 1024-block grid (4 blocks/CU exact)

typedef __bf16 bf16_t;
typedef __bf16 bf16x8 __attribute__((ext_vector_type(8)));
typedef float  f32x16 __attribute__((ext_vector_type(16)));

#define NPTS    8192
#define NB      4
#define NSETPTS (NB * NPTS)          // 32768 points per set
#define TPB     256
#define WAVES   4
#define QC      (WAVES * 32)         // 128 query rows per block
#define QPANELS (NPTS / QC)          // 64
#define SEGR    2                    // ref-dim split
#define RC      (NPTS / SEGR)        // 4096 refs per block sweep
#define RT      (RC / 32)            // 128 r-tiles per sweep (pair-iters: 64)

__global__ void chamfer_init_out(unsigned int* __restrict__ out, int n) {
    int i = blockIdx.x * blockDim.x + threadIdx.x;
    if (i < n) out[i] = 0x7F800000u;  // +inf bits
}

__device__ __forceinline__ void split2(float v, bf16_t& h, bf16_t& l) {
    h = (bf16_t)v;
    l = (bf16_t)(v - (float)h);
}

// Per-point K=16 slot vectors (A-side and B-side), stored pre-permuted so a
// lane's fragment load is one 16B load: stored[j] = logical[perm[j]],
// perm = {0,1,2,3, 8,9,10,11, 4,5,6,7, 12,13,14,15}.
// Slots: k0-2 (-2q)_hi*r_hi | k3-5 (-2q)_lo*r_hi | k6-8 (-2q)_hi*r_lo |
//        k9-10 |q|^2 hi/lo * 1 | k11-12 1 * |r|^2 hi/lo | k13-15 zero.
__global__ void chamfer_prep(const float* __restrict__ xyz1,
                             const float* __restrict__ xyz2,
                             bf16_t* __restrict__ a16,
                             bf16_t* __restrict__ b16) {
    int i = blockIdx.x * blockDim.x + threadIdx.x;   // 0..2*NSETPTS-1
    const float* src = (i >= NSETPTS) ? xyz2 : xyz1;
    int p = i & (NSETPTS - 1);
    float x = src[3 * p], y = src[3 * p + 1], z = src[3 * p + 2];
    float sq = x * x + y * y + z * z;

    bf16_t m2xh, m2xl, m2yh, m2yl, m2zh, m2zl;
    split2(-2.f * x, m2xh, m2xl);
    split2(-2.f * y, m2yh, m2yl);
    split2(-2.f * z, m2zh, m2zl);
    bf16_t xh, xl, yh, yl, zh, zl;
    split2(x, xh, xl); split2(y, yh, yl); split2(z, zh, zl);
    bf16_t sqh, sql;
    split2(sq, sqh, sql);
    bf16_t one = (bf16_t)1.0f, zero = (bf16_t)0.0f;

    bf16_t A[16]  = { m2xh, m2yh, m2zh,  m2xl, m2yl, m2zl,
                      m2xh, m2yh, m2zh,  sqh, sql, one, one, zero, zero, zero };
    bf16_t Bv[16] = { xh, yh, zh,  xh, yh, zh,  xl, yl, zl,
                      one, one, sqh, sql, zero, zero, zero };

    const int perm[16] = {0,1,2,3, 8,9,10,11, 4,5,6,7, 12,13,14,15};
    bf16_t* ao = a16 + (size_t)i * 16;
    bf16_t* bo = b16 + (size_t)i * 16;
#pragma unroll
    for (int j = 0; j < 16; ++j) { ao[j] = A[perm[j]]; bo[j] = Bv[perm[j]]; }
}

__global__ __launch_bounds__(TPB, 4) void chamfer_main(
    const bf16_t* __restrict__ a16,
    const bf16_t* __restrict__ b16,
    unsigned int* __restrict__ out)
{
    __shared__ float red[WAVES][32][33];   // ~16.9 KB (+1 pad)

    int bid = blockIdx.x;
    int s   = bid & (SEGR - 1);    bid >>= 1;   // reference segment
    int qp  = bid & (QPANELS - 1); bid >>= 6;   // q-panel
    int b   = bid & 3;             bid >>= 2;   // batch
    int dir = bid;                              // 0: q=xyz1,r=xyz2 ; 1: swapped

    int wave = threadIdx.x >> 6;
    int lane = threadIdx.x & 63;
    int col  = lane & 31;                    // A-row / B-col index
    int h    = lane >> 5;                    // k sub-group

    const bf16_t* ap = a16 + ((size_t)dir * NB + b) * NPTS * 16;
    const bf16_t* bp = b16 + ((size_t)(1 - dir) * NB + b) * NPTS * 16;

    int qbase = qp * QC + wave * 32;
    bf16x8 af = *((const bf16x8*)(ap + (size_t)(qbase + col) * 16) + h);

    const bf16x8* bptr = (const bf16x8*)(bp + (size_t)(s * RC) * 16) + h;
    // tile t fragment for this lane: bptr[col*2 + t*64]
    const bf16x8* bl = bptr + col * 2;

    f32x16 rm, zacc;
#pragma unroll
    for (int g = 0; g < 16; ++g) { rm[g] = INFINITY; zacc[g] = 0.f; }

    // 6-register tile ring: compute (c0,c1), staged (d0,d1), in-flight (p0,p1).
    bf16x8 c0 = bl[0 * 64];
    bf16x8 c1 = bl[1 * 64];
    bf16x8 d0 = bl[2 * 64];
    bf16x8 d1 = bl[3 * 64];
    for (int t = 0; t < RT; t += 2) {
        int n0 = (t + 4 < RT) ? (t + 4) : 0;   // tail: inert reload of tile 0
        int n1 = (t + 5 < RT) ? (t + 5) : 0;
        bf16x8 p0 = bl[(size_t)n0 * 64];
        bf16x8 p1 = bl[(size_t)n1 * 64];

        f32x16 a0 = __builtin_amdgcn_mfma_f32_32x32x16_bf16(af, c0, zacc, 0, 0, 0);
        f32x16 a1 = __builtin_amdgcn_mfma_f32_32x32x16_bf16(af, c1, zacc, 0, 0, 0);
#pragma unroll
        for (int g = 0; g < 16; ++g)
            rm[g] = fminf(fminf(a0[g], a1[g]), rm[g]);   // fuses to v_min3_f32

        c0 = d0; c1 = d1;
        d0 = p0; d1 = p1;
    }

    // Scatter running row-mins: D row = (g&3) + 8*(g>>2) + 4*h (verified layout).
#pragma unroll
    for (int g = 0; g < 16; ++g) {
        int row = (g & 3) + 8 * (g >> 2) + 4 * h;
        red[wave][row][col] = rm[g];
    }
    __syncthreads();

    // Threads 0..127: reduce 32 col-slots for one q-row, clamp, publish.
    if (threadIdx.x < QC) {
        int w = threadIdx.x >> 5, r = threadIdx.x & 31;
        const float* rp = &red[w][r][0];
        float v0 = rp[0], v1 = rp[1], v2 = rp[2], v3 = rp[3];
#pragma unroll
        for (int c = 4; c < 32; c += 4) {
            v0 = fminf(v0, rp[c + 0]);
            v1 = fminf(v1, rp[c + 1]);
            v2 = fminf(v2, rp[c + 2]);
            v3 = fminf(v3, rp[c + 3]);
        }
        float v = fmaxf(fminf(fminf(v0, v1), fminf(v2, v3)), 0.f);
        unsigned idx = (unsigned)(dir * NSETPTS + b * NPTS + qp * QC + threadIdx.x);
        atomicMin(&out[idx], __float_as_uint(v));
    }
}

extern "C" void kernel_launch(void* const* d_in, const int* in_sizes, int n_in,
                              void* d_out, int out_size, void* d_ws, size_t ws_size,
                              hipStream_t stream) {
    const float* xyz1 = (const float*)d_in[0];
    const float* xyz2 = (const float*)d_in[1];
    unsigned int* out = (unsigned int*)d_out;

    bf16_t* a16 = (bf16_t*)d_ws;                          // 2 MB
    bf16_t* b16 = a16 + (size_t)2 * NSETPTS * 16;         // +2 MB

    hipLaunchKernelGGL(chamfer_init_out,
                       dim3((out_size + TPB - 1) / TPB), dim3(TPB), 0, stream,
                       out, out_size);

    hipLaunchKernelGGL(chamfer_prep,
                       dim3(2 * NSETPTS / TPB), dim3(TPB), 0, stream,
                       xyz1, xyz2, a16, b16);

    // 2 dirs x 4 batches x 64 q-panels x 2 ref-segments = 1024 blocks
    hipLaunchKernelGGL(chamfer_main,
                       dim3(2 * NB * QPANELS * SEGR), dim3(TPB), 0, stream,
                       a16, b16, out);
}